// Round 8
// baseline (62.320 us; speedup 1.0000x reference)
//
#include <hip/hip_runtime.h>
#include <stdint.h>

typedef __bf16 bf16_t;
typedef __bf16 bf16x8 __attribute__((ext_vector_type(8)));
typedef float f32x4 __attribute__((ext_vector_type(4)));
typedef unsigned short ushort8 __attribute__((ext_vector_type(8)));

#define M_DIM 16384
#define N_DIM 1024
#define K_DIM 1024
#define BM 128
#define BN 256
#define BK 32
#define NT (K_DIM / BK)        // 32 K-tiles
#define ASLOT (BM * BK)        // 4096 elems = 8 KB
#define BSLOT (BN * BK)        // 8192 elems = 16 KB
#define BBASE (3 * ASLOT)      // B region after 3 A slots
// LDS total: 3*8KB + 3*16KB = 72 KB -> 2 blocks/CU (144 KB of 160)

// ---------------- x: f32 -> bf16 (RNE), vectorized ----------------
__global__ void cvt_x_bf16(const float* __restrict__ x,
                           unsigned short* __restrict__ xb, int n8) {
    int i = blockIdx.x * blockDim.x + threadIdx.x;
    int stride = gridDim.x * blockDim.x;
    for (; i < n8; i += stride) {
        const float4* p = (const float4*)(x + (size_t)i * 8);
        float4 v0 = p[0], v1 = p[1];
        float vv[8] = {v0.x, v0.y, v0.z, v0.w, v1.x, v1.y, v1.z, v1.w};
        ushort8 o;
#pragma unroll
        for (int j = 0; j < 8; ++j) {
            uint32_t u = __builtin_bit_cast(uint32_t, vv[j]);
            u = u + 0x7FFFu + ((u >> 16) & 1u);   // round-to-nearest-even
            o[j] = (unsigned short)(u >> 16);
        }
        *(ushort8*)(xb + (size_t)i * 8) = o;
    }
}

// ------- W: binarize (exact reference semantics) + transpose to [N][K] -------
__global__ void bin_transpose_w(const float* __restrict__ W,
                                unsigned short* __restrict__ WbT) {
    __shared__ unsigned short t[64][68];
    int tj = blockIdx.x;                   // n tile
    int ti = blockIdx.y;                   // k tile
    int tid = threadIdx.x;
    int c4 = (tid & 15) * 4;
    int r0 = tid >> 4;
#pragma unroll
    for (int p = 0; p < 4; ++p) {
        int r = r0 + p * 16;
        float4 v = *(const float4*)(W + (size_t)(ti * 64 + r) * N_DIM + tj * 64 + c4);
        // reference: +1 iff (w+1)/2 > 0.5 (round-half-even at exactly 0.5 -> -1)
        t[r][c4 + 0] = ((v.x + 1.0f) * 0.5f > 0.5f) ? 0x3F80 : 0xBF80;
        t[r][c4 + 1] = ((v.y + 1.0f) * 0.5f > 0.5f) ? 0x3F80 : 0xBF80;
        t[r][c4 + 2] = ((v.z + 1.0f) * 0.5f > 0.5f) ? 0x3F80 : 0xBF80;
        t[r][c4 + 3] = ((v.w + 1.0f) * 0.5f > 0.5f) ? 0x3F80 : 0xBF80;
    }
    __syncthreads();
#pragma unroll
    for (int p = 0; p < 4; ++p) {
        int rn = r0 + p * 16;
        ushort4 o;
        o.x = t[c4 + 0][rn];
        o.y = t[c4 + 1][rn];
        o.z = t[c4 + 2][rn];
        o.w = t[c4 + 3][rn];
        *(ushort4*)(WbT + (size_t)(tj * 64 + rn) * K_DIM + ti * 64 + c4) = o;
    }
}

// ------- 2-blocks/CU TLP-overlapped bf16 GEMM (16x16x32 MFMA) -------
__device__ __forceinline__ void gload16(const bf16_t* g, const bf16_t* l) {
    __builtin_amdgcn_global_load_lds(
        (const __attribute__((address_space(1))) void*)(g),
        (__attribute__((address_space(3))) void*)(l),
        16, 0, 0);
}

__global__ __launch_bounds__(512, 4) void bgemm(const bf16_t* __restrict__ A,
                                                const bf16_t* __restrict__ Bt,
                                                const float* __restrict__ bias,
                                                float* __restrict__ C) {
    __shared__ __align__(16) bf16_t lds[3 * ASLOT + 3 * BSLOT];   // 72 KB

    const int nwg = (M_DIM / BM) * (N_DIM / BN);   // 512, %8==0
    int bid = blockIdx.x;
    int swz = (bid & 7) * (nwg >> 3) + (bid >> 3); // XCD-aware, bijective
    int tile_n = swz & 3;                          // consecutive swz share A panel
    int tile_m = swz >> 2;
    int bm0 = tile_m * BM;
    int bn0 = tile_n * BN;

    int tid = threadIdx.x;
    int w = tid >> 6, l = tid & 63;    // 8 waves: 2(M) x 4(N)
    int wr = w >> 2, wc = w & 3;       // per-wave 64x64 output
    int lr = l & 15, lk = l >> 4;
    int rsw = (lr >> 1) & 3;           // read-side XOR selector (row>>1)&3

    // staging: linear LDS dest (lane-contiguous 16B); swizzle via pre-swizzled
    // per-lane GLOBAL source chunk (both-sides rule). Row = 64 B = 4 chunks.
    int srow = tid >> 2;                       // 0..127 per call
    int schunk = (tid & 3) ^ ((srow >> 1) & 3);
    auto stageA = [&](int t) {                 // 1 call = 8 KB = full A tile
        gload16(A + (size_t)(bm0 + srow) * K_DIM + t * BK + schunk * 8,
                lds + (t % 3) * ASLOT + tid * 8);
    };
    auto stageB = [&](int t, int c) {          // 2 calls of 8 KB
        gload16(Bt + (size_t)(bn0 + c * 128 + srow) * K_DIM + t * BK + schunk * 8,
                lds + BBASE + (t % 3) * BSLOT + c * 4096 + tid * 8);
    };

    f32x4 acc[4][4];
#pragma unroll
    for (int m = 0; m < 4; ++m)
#pragma unroll
        for (int n = 0; n < 4; ++n)
            acc[m][n] = (f32x4)(0.0f);

    // ---- prologue: stage tiles 0,1; retire tile 0 (tile 1's 3 in flight) ----
    stageA(0); stageB(0, 0); stageB(0, 1);
    stageA(1); stageB(1, 0); stageB(1, 1);
    asm volatile("s_waitcnt vmcnt(3)" ::: "memory");
    __builtin_amdgcn_s_barrier();

    for (int t = 0; t < NT; ++t) {
        // ---- stage tile t+2 early (slot (t+2)%3 is free: t+1 in flight, t resident)
        if (t + 2 < NT) { stageA(t + 2); stageB(t + 2, 0); stageB(t + 2, 1); }

        const bf16_t* Ab = lds + (t % 3) * ASLOT;
        const bf16_t* Bb = lds + BBASE + (t % 3) * BSLOT;

        // ---- free-running compute; cross-block TLP provides pipe overlap ----
        bf16x8 bfr[4], afr[4];
#pragma unroll
        for (int n = 0; n < 4; ++n)
            bfr[n] = *(const bf16x8*)(Bb + (wc * 64 + n * 16 + lr) * BK
                                      + ((lk ^ rsw) * 8));
#pragma unroll
        for (int m = 0; m < 4; ++m)
            afr[m] = *(const bf16x8*)(Ab + (wr * 64 + m * 16 + lr) * BK
                                      + ((lk ^ rsw) * 8));
#pragma unroll
        for (int m = 0; m < 4; ++m)
#pragma unroll
            for (int n = 0; n < 4; ++n)
                acc[m][n] = __builtin_amdgcn_mfma_f32_16x16x32_bf16(
                    afr[m], bfr[n], acc[m][n], 0, 0, 0);

        // ---- boundary: retire tile t+1 (3 calls); keep t+2's 3 in flight ----
        if (t + 1 < NT) {
            if (t + 2 < NT)
                asm volatile("s_waitcnt vmcnt(3)" ::: "memory");
            else
                asm volatile("s_waitcnt vmcnt(0)" ::: "memory");
            __builtin_amdgcn_s_barrier();
        }
    }

    // ---- epilogue: C/D layout col = lane&15, row = (lane>>4)*4 + reg ----
#pragma unroll
    for (int n = 0; n < 4; ++n) {
        int col = bn0 + wc * 64 + n * 16 + lr;
        float bv = bias[col];
#pragma unroll
        for (int m = 0; m < 4; ++m) {
            int row0 = bm0 + wr * 64 + m * 16 + lk * 4;
#pragma unroll
            for (int j = 0; j < 4; ++j)
                C[(size_t)(row0 + j) * N_DIM + col] = acc[m][n][j] + bv;
        }
    }
}

// ---------------- fallback (only if workspace too small) ----------------
__global__ void naive_bin_dense(const float* __restrict__ x,
                                const float* __restrict__ W,
                                const float* __restrict__ b,
                                float* __restrict__ out) {
    int col = blockIdx.x * 256 + threadIdx.x;
    int row = blockIdx.y;
    float acc = 0.0f;
    for (int k = 0; k < K_DIM; ++k) {
        float s = ((W[(size_t)k * N_DIM + col] + 1.0f) * 0.5f > 0.5f) ? 1.0f : -1.0f;
        acc += x[(size_t)row * K_DIM + k] * s;
    }
    out[(size_t)row * N_DIM + col] = acc + b[col];
}

extern "C" void kernel_launch(void* const* d_in, const int* in_sizes, int n_in,
                              void* d_out, int out_size, void* d_ws, size_t ws_size,
                              hipStream_t stream) {
    const float* x = (const float*)d_in[0];
    const float* W = (const float*)d_in[1];
    const float* b = (const float*)d_in[2];
    float* out = (float*)d_out;

    size_t xb_bytes = (size_t)M_DIM * K_DIM * sizeof(unsigned short);
    size_t wb_bytes = (size_t)K_DIM * N_DIM * sizeof(unsigned short);

    if (ws_size >= xb_bytes + wb_bytes) {
        unsigned short* xb = (unsigned short*)d_ws;
        unsigned short* wbt = (unsigned short*)((char*)d_ws + xb_bytes);
        hipLaunchKernelGGL(bin_transpose_w, dim3(N_DIM / 64, K_DIM / 64), dim3(256),
                           0, stream, W, wbt);
        hipLaunchKernelGGL(cvt_x_bf16, dim3(2048), dim3(256), 0, stream,
                           x, xb, (M_DIM * K_DIM) / 8);
        hipLaunchKernelGGL(bgemm, dim3((M_DIM / BM) * (N_DIM / BN)), dim3(512), 0, stream,
                           (const bf16_t*)xb, (const bf16_t*)wbt, b, out);
    } else {
        hipLaunchKernelGGL(naive_bin_dense, dim3(N_DIM / 256, M_DIM), dim3(256),
                           0, stream, x, W, b, out);
    }
}

// Round 9
// 54.887 us; speedup vs baseline: 1.1354x; 1.1354x over previous
//
#include <hip/hip_runtime.h>
#include <stdint.h>

typedef __bf16 bf16_t;
typedef __bf16 bf16x8 __attribute__((ext_vector_type(8)));
typedef float f32x4 __attribute__((ext_vector_type(4)));

#define M_DIM 16384
#define N_DIM 1024
#define K_DIM 1024
#define BM 128
#define BN 256
#define BK 32
#define NT (K_DIM / BK)          // 32 K-tiles
#define A_SLOT 16384             // bytes: 128 rows x 32 k x 4B (f32)
#define B_SLOT 16384             // bytes: 256 rows x 32 k x 2B (bf16)
#define B_BASE 32768             // byte offset of B region
// LDS: A[2] + B[2] = 64 KB -> 2 blocks/CU (128 of 160 KB)

// ------- W: binarize (exact reference semantics) + transpose to [N][K] -------
__global__ void bin_transpose_w(const float* __restrict__ W,
                                unsigned short* __restrict__ WbT) {
    __shared__ unsigned short t[64][68];
    int tj = blockIdx.x;                   // n tile
    int ti = blockIdx.y;                   // k tile
    int tid = threadIdx.x;
    int c4 = (tid & 15) * 4;
    int r0 = tid >> 4;
#pragma unroll
    for (int p = 0; p < 4; ++p) {
        int r = r0 + p * 16;
        float4 v = *(const float4*)(W + (size_t)(ti * 64 + r) * N_DIM + tj * 64 + c4);
        // reference: +1 iff (w+1)/2 > 0.5 (round-half-even at exactly 0.5 -> -1)
        t[r][c4 + 0] = ((v.x + 1.0f) * 0.5f > 0.5f) ? 0x3F80 : 0xBF80;
        t[r][c4 + 1] = ((v.y + 1.0f) * 0.5f > 0.5f) ? 0x3F80 : 0xBF80;
        t[r][c4 + 2] = ((v.z + 1.0f) * 0.5f > 0.5f) ? 0x3F80 : 0xBF80;
        t[r][c4 + 3] = ((v.w + 1.0f) * 0.5f > 0.5f) ? 0x3F80 : 0xBF80;
    }
    __syncthreads();
#pragma unroll
    for (int p = 0; p < 4; ++p) {
        int rn = r0 + p * 16;
        ushort4 o;
        o.x = t[c4 + 0][rn];
        o.y = t[c4 + 1][rn];
        o.z = t[c4 + 2][rn];
        o.w = t[c4 + 3][rn];
        *(ushort4*)(WbT + (size_t)(tj * 64 + rn) * K_DIM + ti * 64 + c4) = o;
    }
}

// ------- fused cvt-on-read GEMM: C = cvt_bf16(X) * Bt^T + bias -------
__device__ __forceinline__ void gload16(const void* g, const void* l) {
    __builtin_amdgcn_global_load_lds(
        (const __attribute__((address_space(1))) void*)(g),
        (__attribute__((address_space(3))) void*)(l),
        16, 0, 0);
}

__global__ __launch_bounds__(512, 4) void bgemm(const float* __restrict__ X,
                                                const bf16_t* __restrict__ Bt,
                                                const float* __restrict__ bias,
                                                float* __restrict__ C) {
    __shared__ __align__(16) char lds[2 * A_SLOT + 2 * B_SLOT];   // 64 KB

    const int nwg = (M_DIM / BM) * (N_DIM / BN);   // 512, %8==0
    int bid = blockIdx.x;
    int swz = (bid & 7) * (nwg >> 3) + (bid >> 3); // XCD-aware, bijective
    int tile_n = swz & 3;                          // consecutive swz share A panel
    int tile_m = swz >> 2;
    int bm0 = tile_m * BM;
    int bn0 = tile_n * BN;

    int tid = threadIdx.x;
    int w = tid >> 6, l = tid & 63;    // 8 waves: 2(M) x 4(N)
    int wr = w >> 2, wc = w & 3;       // per-wave 64x64 output
    int lr = l & 15, lk = l >> 4;

    // ---- staging (both via gload_lds, linear LDS dest, pre-swizzled source) ----
    // A (f32): row has 8 x 16B chunks; stored chunk slot = chunk ^ (row&7)
    int arow = tid >> 3;                       // 0..63 per call (+c*64)
    int achk = (tid & 7) ^ (arow & 7);         // logical chunk at this slot
    auto stageA = [&](int t, int c) {
        gload16(X + (size_t)(bm0 + c * 64 + arow) * K_DIM + t * BK + achk * 4,
                lds + (t & 1) * A_SLOT + c * 8192 + tid * 16);
    };
    // B (bf16): row has 4 x 16B chunks; stored slot = chunk ^ ((row>>1)&3)
    int brow = tid >> 2;                       // 0..127 per call (+c*128)
    int bchk = (tid & 3) ^ ((brow >> 1) & 3);
    auto stageB = [&](int t, int c) {
        gload16(Bt + (size_t)(bn0 + c * 128 + brow) * K_DIM + t * BK + bchk * 8,
                lds + B_BASE + (t & 1) * B_SLOT + c * 8192 + tid * 16);
    };

    f32x4 acc[4][4];
#pragma unroll
    for (int m = 0; m < 4; ++m)
#pragma unroll
        for (int n = 0; n < 4; ++n)
            acc[m][n] = (f32x4)(0.0f);

    // ---- prologue: stage tile 0, drain, barrier ----
    stageA(0, 0); stageA(0, 1); stageB(0, 0); stageB(0, 1);
    asm volatile("s_waitcnt vmcnt(0)" ::: "memory");
    __builtin_amdgcn_s_barrier();

    for (int t = 0; t < NT; ++t) {
        // ---- stage tile t+1 early (opposite slot; last read at t-1, retired) ----
        if (t + 1 < NT) {
            stageA(t + 1, 0); stageA(t + 1, 1);
            stageB(t + 1, 0); stageB(t + 1, 1);
        }

        const char* Ab = lds + (t & 1) * A_SLOT;
        const char* Bb = lds + B_BASE + (t & 1) * B_SLOT;

        // ---- B frags: bf16 direct (swizzled read) ----
        bf16x8 bfr[4];
#pragma unroll
        for (int n = 0; n < 4; ++n) {
            int br = wc * 64 + n * 16 + lr;
            bfr[n] = *(const bf16x8*)(Bb + br * 64 + ((lk ^ ((br >> 1) & 3)) * 16));
        }
        // ---- A frags: f32 2xb128 reads + in-register RNE cvt, then MFMA ----
#pragma unroll
        for (int m = 0; m < 4; ++m) {
            int r = wr * 64 + m * 16 + lr;
            const char* rb = Ab + r * 128;
            float4 lo = *(const float4*)(rb + (((2 * lk) ^ (r & 7)) * 16));
            float4 hi = *(const float4*)(rb + (((2 * lk + 1) ^ (r & 7)) * 16));
            bf16x8 afr;
            afr[0] = (__bf16)lo.x; afr[1] = (__bf16)lo.y;
            afr[2] = (__bf16)lo.z; afr[3] = (__bf16)lo.w;
            afr[4] = (__bf16)hi.x; afr[5] = (__bf16)hi.y;
            afr[6] = (__bf16)hi.z; afr[7] = (__bf16)hi.w;
#pragma unroll
            for (int n = 0; n < 4; ++n)
                acc[m][n] = __builtin_amdgcn_mfma_f32_16x16x32_bf16(
                    afr, bfr[n], acc[m][n], 0, 0, 0);
        }

        // ---- boundary: drain staging of t+1, rendezvous ----
        if (t + 1 < NT) {
            asm volatile("s_waitcnt vmcnt(0)" ::: "memory");
            __builtin_amdgcn_s_barrier();
        }
    }

    // ---- epilogue: C/D layout col = lane&15, row = (lane>>4)*4 + reg ----
#pragma unroll
    for (int n = 0; n < 4; ++n) {
        int col = bn0 + wc * 64 + n * 16 + lr;
        float bv = bias[col];
#pragma unroll
        for (int m = 0; m < 4; ++m) {
            int row0 = bm0 + wr * 64 + m * 16 + lk * 4;
#pragma unroll
            for (int j = 0; j < 4; ++j)
                C[(size_t)(row0 + j) * N_DIM + col] = acc[m][n][j] + bv;
        }
    }
}

// ---------------- fallback (only if workspace too small) ----------------
__global__ void naive_bin_dense(const float* __restrict__ x,
                                const float* __restrict__ W,
                                const float* __restrict__ b,
                                float* __restrict__ out) {
    int col = blockIdx.x * 256 + threadIdx.x;
    int row = blockIdx.y;
    float acc = 0.0f;
    for (int k = 0; k < K_DIM; ++k) {
        float s = ((W[(size_t)k * N_DIM + col] + 1.0f) * 0.5f > 0.5f) ? 1.0f : -1.0f;
        acc += x[(size_t)row * K_DIM + k] * s;
    }
    out[(size_t)row * N_DIM + col] = acc + b[col];
}

extern "C" void kernel_launch(void* const* d_in, const int* in_sizes, int n_in,
                              void* d_out, int out_size, void* d_ws, size_t ws_size,
                              hipStream_t stream) {
    const float* x = (const float*)d_in[0];
    const float* W = (const float*)d_in[1];
    const float* b = (const float*)d_in[2];
    float* out = (float*)d_out;

    size_t wb_bytes = (size_t)K_DIM * N_DIM * sizeof(unsigned short);

    if (ws_size >= wb_bytes) {
        unsigned short* wbt = (unsigned short*)d_ws;
        hipLaunchKernelGGL(bin_transpose_w, dim3(N_DIM / 64, K_DIM / 64), dim3(256),
                           0, stream, W, wbt);
        hipLaunchKernelGGL(bgemm, dim3((M_DIM / BM) * (N_DIM / BN)), dim3(512), 0, stream,
                           x, (const bf16_t*)wbt, b, out);
    } else {
        hipLaunchKernelGGL(naive_bin_dense, dim3(N_DIM / 256, M_DIM), dim3(256),
                           0, stream, x, W, b, out);
    }
}